// Round 4
// baseline (116.946 us; speedup 1.0000x reference)
//
#include <hip/hip_runtime.h>
#include <math.h>

#define NFFT 4096
#define HALF 2048
#define LSEG 2048   // L
#define SSZ 4096    // STATE_SIZE

typedef float v2f __attribute__((ext_vector_type(2)));
typedef float v4f __attribute__((ext_vector_type(4)));

// ---------------- verified packed-f32 complex primitives (R1/R3-passing set) ----------------
// cmul: r = {a.x*b.x - a.y*b.y, a.x*b.y + a.y*b.x}
static __device__ __forceinline__ v2f cmul(v2f a, v2f b) {
    v2f r;
    asm("v_pk_mul_f32 %0, %1, %2 op_sel:[0,0] op_sel_hi:[0,1]\n\t"
        "v_pk_fma_f32 %0, %1, %2, %0 op_sel:[1,1,0] op_sel_hi:[1,0,1] neg_lo:[1,0,0]"
        : "=&v"(r) : "v"(a), "v"(b));
    return r;
}
// c + {d.y, -d.x}   (== C - iD·i ... forward -i rotation)
static __device__ __forceinline__ v2f cadd_mi(v2f c, v2f d) {
    v2f r;
    asm("v_pk_add_f32 %0, %1, %2 op_sel:[0,1] op_sel_hi:[1,0] neg_hi:[0,1]"
        : "=v"(r) : "v"(c), "v"(d));
    return r;
}
// c + {-d.y, d.x}   (inverse +i rotation)
static __device__ __forceinline__ v2f cadd_pi(v2f c, v2f d) {
    v2f r;
    asm("v_pk_add_f32 %0, %1, %2 op_sel:[0,1] op_sel_hi:[1,0] neg_lo:[0,1]"
        : "=v"(r) : "v"(c), "v"(d));
    return r;
}

static __device__ __forceinline__ int PAD(int i) { return i + (i >> 4); }

// DFT-8 via two DFT-4s (even/odd) + w8 combine. Verified on delta inputs, both signs.
template <int SGN>
static __device__ __forceinline__ void dft8(v2f r[8]) {
    // DFT4 of evens (r0,r2,r4,r6)
    v2f A0 = r[0] + r[4], C0 = r[0] - r[4];
    v2f B0 = r[2] + r[6], D0 = r[2] - r[6];
    v2f E0 = A0 + B0, E2 = A0 - B0;
    v2f E1 = (SGN < 0) ? cadd_mi(C0, D0) : cadd_pi(C0, D0);
    v2f E3 = (SGN < 0) ? cadd_pi(C0, D0) : cadd_mi(C0, D0);
    // DFT4 of odds (r1,r3,r5,r7)
    v2f A1 = r[1] + r[5], C1 = r[1] - r[5];
    v2f B1 = r[3] + r[7], D1 = r[3] - r[7];
    v2f O0 = A1 + B1, O2 = A1 - B1;
    v2f O1 = (SGN < 0) ? cadd_mi(C1, D1) : cadd_pi(C1, D1);
    v2f O3 = (SGN < 0) ? cadd_pi(C1, D1) : cadd_mi(C1, D1);
    const float HQ = 0.70710678118654752f;
    const float S = (float)SGN;
    v2f T1 = cmul(O1, (v2f){HQ, S * HQ});     // w8^1
    v2f T3 = cmul(O3, (v2f){-HQ, S * HQ});    // w8^3
    r[0] = E0 + O0;  r[4] = E0 - O0;
    r[1] = E1 + T1;  r[5] = E1 - T1;
    r[2] = (SGN < 0) ? cadd_mi(E2, O2) : cadd_pi(E2, O2);   // w8^2 = -S*i ... = S*i
    r[6] = (SGN < 0) ? cadd_pi(E2, O2) : cadd_mi(E2, O2);
    r[3] = E3 + T3;  r[7] = E3 - T3;
}

// apply r[m] *= w1^m, m=1..7
static __device__ __forceinline__ void twiddle8(v2f r[8], v2f w1) {
    v2f w2 = cmul(w1, w1);
    v2f w3 = cmul(w2, w1);
    v2f w4 = cmul(w2, w2);
    v2f w5 = cmul(w4, w1);
    v2f w6 = cmul(w3, w3);
    v2f w7 = cmul(w4, w3);
    r[1] = cmul(r[1], w1); r[2] = cmul(r[2], w2); r[3] = cmul(r[3], w3);
    r[4] = cmul(r[4], w4); r[5] = cmul(r[5], w5); r[6] = cmul(r[6], w6);
    r[7] = cmul(r[7], w7);
}

// ---- coefficient kernel: one thread per batch, fp64 DK-method algebra ----
// Writes per-batch {0.5*n0, 0.5*n1, 0.5*sn, d1, sd} to cf_g[b*5..]
__global__ __launch_bounds__(256)
void preamp_coef_kernel(const float* __restrict__ cond,
                        const float* __restrict__ a_rg,
                        const float* __restrict__ a_r1,
                        const float* __restrict__ a_c1,
                        const float* __restrict__ a_c2,
                        const float* __restrict__ cond_w,
                        const float* __restrict__ cond_b,
                        float* __restrict__ cf_g, int B) {
    const int bb = blockIdx.x * 256 + threadIdx.x;
    if (bb >= B) return;

    const double RG = (0.9 + (double)(1.0f / (1.0f + expf(-a_rg[0]))) * 0.2) * 1.0e6;
    const double R1 = (0.99 + (double)(1.0f / (1.0f + expf(-a_r1[0]))) * 0.02) * 4.7e5;
    const double C1 = (0.9 + (double)(1.0f / (1.0f + expf(-a_c1[0]))) * 0.2) * 3.3e-9;
    const double C2 = (0.9 + (double)(1.0f / (1.0f + expf(-a_c2[0]))) * 0.2) * 1.0e-9;
    const double g1 = 1.0 / R1;
    const double gc1 = 2.0 * C1 * 44100.0;
    const double gc2 = 2.0 * C2 * 44100.0;

    float zf = cond[bb] * cond_w[0] + cond_b[0];
    float pot = 1.0f / (1.0f + expf(-zf));
    float prf = (powf(10.0f, pot) - 1.0f) / 9.0f;
    prf = fminf(fmaxf(prf, 1e-4f), 1.0f - 1e-4f);
    const double p = (double)prf;

    // Analytic So^{-1}
    const double ds = gc1 + g1;
    double S[4][4] = {
        {0.0, 0.0,        0.0,       1.0},
        {0.0, 1.0 / ds,   0.0,       gc1 / ds},
        {0.0, 0.0,        1.0 / gc2, 0.0},
        {1.0, gc1 / ds,   0.0,       -gc1 * g1 / ds}};

    double Q00 = S[1][1] - S[1][2] - S[2][1] + S[2][2];
    double Q01 = S[1][2] - S[2][2];
    double Q10 = S[2][1] - S[2][2];
    double Q11 = S[2][2];

    double Ux00 = S[0][1] - S[0][2] - S[1][1] + S[1][2];
    double Ux01 = S[0][2] - S[1][2];
    double Ux10 = S[2][1] - S[2][2];
    double Ux11 = S[2][2];

    double Uo0 = S[2][1] - S[2][2], Uo1 = S[2][2];
    double Uu0 = S[3][1] - S[3][2], Uu1 = S[3][2];

    double P00 = S[0][0] - S[0][1] - S[1][0] + S[1][1];
    double P01 = S[0][2] - S[1][2];
    double P10 = S[2][0] - S[2][1];
    double P11 = S[2][2];

    double Ao00 = 2.0 * gc1 * P00 - 1.0, Ao01 = 2.0 * gc1 * P01;
    double Ao10 = 2.0 * gc2 * P10,       Ao11 = 2.0 * gc2 * P11 - 1.0;

    double Bo0 = 2.0 * gc1 * (S[0][3] - S[1][3]);
    double Bo1 = 2.0 * gc2 * S[2][3];

    double Do0 = S[2][0] - S[2][1], Do1 = S[2][2];
    double Eo  = S[2][3];

    double T00 = 2.0 * gc1 * Ux00, T01 = 2.0 * gc1 * Ux01;
    double T10 = 2.0 * gc2 * Ux10, T11 = 2.0 * gc2 * Ux11;

    double d0 = (1.0 - p) * RG, d1v = p * RG;
    double M00 = d0 + Q00, M01 = Q01, M10 = Q10, M11 = d1v + Q11;
    double idet = 1.0 / (M00 * M11 - M01 * M10);
    double G00 =  M11 * idet, G01 = -M01 * idet;
    double G10 = -M10 * idet, G11 =  M00 * idet;

    double TG00 = T00 * G00 + T01 * G10, TG01 = T00 * G01 + T01 * G11;
    double TG10 = T10 * G00 + T11 * G10, TG11 = T10 * G01 + T11 * G11;

    double A00 = Ao00 - (TG00 * Ux00 + TG01 * Ux01);
    double A01 = Ao01 - (TG00 * Ux10 + TG01 * Ux11);
    double A10 = Ao10 - (TG10 * Ux00 + TG11 * Ux01);
    double A11 = Ao11 - (TG10 * Ux10 + TG11 * Ux11);

    double Bm0 = Bo0 - (TG00 * Uu0 + TG01 * Uu1);
    double Bm1 = Bo1 - (TG10 * Uu0 + TG11 * Uu1);

    double w0v = Uo0 * G00 + Uo1 * G10, w1v = Uo0 * G01 + Uo1 * G11;
    double Dm0 = Do0 - (w0v * Ux00 + w1v * Ux01);
    double Dm1 = Do1 - (w0v * Ux10 + w1v * Ux11);
    double Em  = Eo  - (w0v * Uu0 + w1v * Uu1);

    double den1 = -(A00 + A11);
    double den2 = A00 * A11 - A01 * A10;
    double Mm00 = A00 - Bm0 * Dm0, Mm01 = A01 - Bm0 * Dm1;
    double Mm10 = A10 - Bm1 * Dm0, Mm11 = A11 - Bm1 * Dm1;
    double num0 = Em;
    double num1 = -(Mm00 + Mm11) + (Em - 1.0) * den1;
    double num2 = (Mm00 * Mm11 - Mm01 * Mm10) + (Em - 1.0) * den2;

    float* o = cf_g + (size_t)bb * 5;
    o[0] = (float)(0.5 * num0);                    // 0.5: Hermitian factor folded (exact)
    o[1] = (float)(0.5 * num1);
    o[2] = (float)(0.5 * (num0 + num1 + num2));    // 0.5*num(1), fp64 sum
    o[3] = (float)den1;
    o[4] = (float)(1.0 + den1 + den2);             // den(1), fp64 sum
}

// ---- main kernel: one block per PAIR of batches, 512 threads, radix-8 FFT ----
// 4096 = 8^4: 4 forward passes + pointwise + 4 inverse passes, 8 pts/thread.
__global__ __launch_bounds__(512, 8)
void preamp_fft_kernel(const float* __restrict__ x,
                       const float* __restrict__ state,
                       const float* __restrict__ cf_g,
                       float* __restrict__ out, int B) {
    __shared__ v2f a_s[NFFT + NFFT / 16];   // padded: 34 KB

    const int t = threadIdx.x;              // 0..511
    const int b0 = 2 * blockIdx.x;
    const int b1 = (b0 + 1 < B) ? b0 + 1 : b0;

    const float* st0 = state + (size_t)b0 * SSZ + (SSZ - LSEG);
    const float* xb0 = x + (size_t)b0 * LSEG;
    const float* st1 = state + (size_t)b1 * SSZ + (SSZ - LSEG);
    const float* xb1 = x + (size_t)b1 * LSEG;

    // staging: float4 loads; q=0 entirely state-half, q=1 entirely x-half
#pragma unroll
    for (int q = 0; q < 2; ++q) {
        const int i0 = (t + 512 * q) << 2;   // multiple of 4, [0,4096)
        v4f fa, fb;
        if (q == 0) {
            fa = *(const v4f*)(st0 + i0);
            fb = *(const v4f*)(st1 + i0);
        } else {
            fa = *(const v4f*)(xb0 + (i0 - LSEG));
            fb = *(const v4f*)(xb1 + (i0 - LSEG));
        }
        const int pp = PAD(i0);              // 4 contiguous padded slots
        a_s[pp + 0] = (v2f){fa.x, fb.x};
        a_s[pp + 1] = (v2f){fa.y, fb.y};
        a_s[pp + 2] = (v2f){fa.z, fb.z};
        a_s[pp + 3] = (v2f){fa.w, fb.w};
    }
    __syncthreads();

    const float TW4096 = 0.00153398078788564f;   // 2*pi/4096
    const float TW512  = 0.01227184630308513f;   // 2*pi/512
    const float TW64   = 0.09817477042468103f;   // 2*pi/64
    const float HW4096 = 0.00076699039394282f;   // pi/4096

    // cached twiddle angles (shared by forward and inverse)
    float swA, cwA;
    __sincosf((float)t * TW4096, &swA, &cwA);
    const int j2 = t & 63, sub2 = t >> 6;
    float swB, cwB;
    __sincosf((float)j2 * TW512, &swB, &cwB);
    const int j3 = t & 7, sub3 = t >> 3;
    float swC, cwC;
    __sincosf((float)j3 * TW64, &swC, &cwC);

    const int base2 = sub2 * 512 + j2;
    const int base3 = sub3 * 64 + j3;
    const int klo = ((t & 7) << 6) | (((t >> 3) & 7) << 3) | (t >> 6);

    v2f r[8];

    // ---- forward pass 1: stride 512 ----
#pragma unroll
    for (int m = 0; m < 8; ++m) r[m] = a_s[PAD(t + 512 * m)];
    dft8<-1>(r);
    twiddle8(r, (v2f){cwA, -swA});
#pragma unroll
    for (int m = 0; m < 8; ++m) a_s[PAD(t + 512 * m)] = r[m];
    __syncthreads();

    // ---- forward pass 2: stride 64 within 512-blocks ----
#pragma unroll
    for (int m = 0; m < 8; ++m) r[m] = a_s[PAD(base2 + 64 * m)];
    dft8<-1>(r);
    twiddle8(r, (v2f){cwB, -swB});
#pragma unroll
    for (int m = 0; m < 8; ++m) a_s[PAD(base2 + 64 * m)] = r[m];
    __syncthreads();

    // ---- forward pass 3: stride 8 within 64-blocks ----
#pragma unroll
    for (int m = 0; m < 8; ++m) r[m] = a_s[PAD(base3 + 8 * m)];
    dft8<-1>(r);
    twiddle8(r, (v2f){cwC, -swC});
#pragma unroll
    for (int m = 0; m < 8; ++m) a_s[PAD(base3 + 8 * m)] = r[m];
    __syncthreads();

    // ---- forward pass 4: span-1 DFT, scatter to natural order ----
#pragma unroll
    for (int m = 0; m < 8; ++m) r[m] = a_s[PAD(8 * t + m)];
    dft8<-1>(r);
    __syncthreads();
#pragma unroll
    for (int m = 0; m < 8; ++m) a_s[PAD((m << 9) | klo)] = r[m];
    __syncthreads();

    // ---- pointwise over Hermitian pairs (k, N-k), uniform 4 iters ----
    {
        const float* cA = cf_g + (size_t)b0 * 5;
        const float* cB = cf_g + (size_t)b1 * 5;
        const v2f n0p = {cA[0], cB[0]};
        const v2f n1p = {cA[1], cB[1]};
        const v2f snp = {cA[2], cB[2]};
        const v2f d1p = {cA[3], cB[3]};
        const v2f sdp = {cA[4], cB[4]};

        for (int j = 0; j < 4; ++j) {
            const int k  = t + 512 * j;                 // 0..2047
            const int kr = (NFFT - k) & (NFFT - 1);
            v2f Wk = a_s[PAD(k)];
            v2f Wr = a_s[PAD(kr)];
            // unscaled Hermitian split (0.5 folded into numerator coefs)
            float Xar = Wk.x + Wr.x, Xai = Wk.y - Wr.y;
            float Xbr = Wk.y + Wr.y, Xbi = Wr.x - Wk.x;
            // u = z-1 = -2*sin(th/2)*(sin(th/2), cos(th/2)), z = e^{-i th}
            float sh, ch;
            __sincosf((float)k * HW4096, &sh, &ch);
            float m2s = -2.0f * sh;
            float ur = m2s * sh, ui = m2s * ch, pr = ur + 2.0f;
            v2f urp = {ur, ur}, uip = {ui, ui}, prp = {pr, pr};

            v2f tr = n0p * prp + n1p;                   // n0*(z+1).re + n1
            v2f ti = n0p * uip;                         // n0*(z+1).im
            v2f nr = snp + urp * tr - uip * ti;
            v2f ni = urp * ti + uip * tr;
            v2f tb = prp + d1p;                         // (z+1).re + d1
            v2f dr = sdp + urp * tb - uip * uip;
            v2f di = urp * uip + uip * tb;
            v2f mg = dr * dr + di * di;
            v2f iv = { __builtin_amdgcn_rcpf(mg.x), __builtin_amdgcn_rcpf(mg.y) };
            v2f Hr = (nr * dr + ni * di) * iv;
            v2f Hi = (ni * dr - nr * di) * iv;

            float Yar = Hr.x * Xar - Hi.x * Xai, Yai = Hr.x * Xai + Hi.x * Xar;
            float Ybr = Hr.y * Xbr - Hi.y * Xbi, Ybi = Hr.y * Xbi + Hi.y * Xbr;
            // Y[k] = Ya + i*Yb ; Y[N-k] = conj(Ya) + i*conj(Yb)
            a_s[PAD(k)]  = (v2f){Yar - Ybi, Yai + Ybr};
            a_s[PAD(kr)] = (v2f){Yar + Ybi, Ybr - Yai};
        }
        // Nyquist bin k = 2048: z = -1, u = -2, (z+1) = 0 -> H is real
        if (t == 0) {
            v2f Wn = a_s[PAD(2048)];
            float Ha = (snp.x - 2.0f * n1p.x) / (sdp.x - 2.0f * d1p.x);
            float Hb = (snp.y - 2.0f * n1p.y) / (sdp.y - 2.0f * d1p.y);
            a_s[PAD(2048)] = (v2f){Ha * (2.0f * Wn.x), Hb * (2.0f * Wn.y)};
        }
    }
    __syncthreads();

    // ---- inverse span-1: gather from natural order, DFT, store base layout ----
#pragma unroll
    for (int m = 0; m < 8; ++m) r[m] = a_s[PAD((m << 9) | klo)];
    dft8<1>(r);
    __syncthreads();
#pragma unroll
    for (int m = 0; m < 8; ++m) a_s[PAD(8 * t + m)] = r[m];
    __syncthreads();

    // ---- inverse pass 3 ----
#pragma unroll
    for (int m = 0; m < 8; ++m) r[m] = a_s[PAD(base3 + 8 * m)];
    twiddle8(r, (v2f){cwC, swC});
    dft8<1>(r);
#pragma unroll
    for (int m = 0; m < 8; ++m) a_s[PAD(base3 + 8 * m)] = r[m];
    __syncthreads();

    // ---- inverse pass 2 ----
#pragma unroll
    for (int m = 0; m < 8; ++m) r[m] = a_s[PAD(base2 + 64 * m)];
    twiddle8(r, (v2f){cwB, swB});
    dft8<1>(r);
#pragma unroll
    for (int m = 0; m < 8; ++m) a_s[PAD(base2 + 64 * m)] = r[m];
    __syncthreads();

    // ---- inverse pass 1 + direct store of last 2048 samples of both batches ----
#pragma unroll
    for (int m = 0; m < 8; ++m) r[m] = a_s[PAD(t + 512 * m)];
    twiddle8(r, (v2f){cwA, swA});
    dft8<1>(r);
    {
        const float scale = 1.0f / (float)NFFT;
        float* ob0 = out + (size_t)b0 * LSEG;
        float* ob1 = out + (size_t)b1 * LSEG;
#pragma unroll
        for (int m = 4; m < 8; ++m) {
            const int idx = t + 512 * (m - 4);   // time sample (t+512m) - 2048
            float ya = r[m].x * scale;
            float yb = (b1 != b0) ? r[m].y * scale : ya;
            ob0[idx] = ya;
            ob1[idx] = yb;
        }
    }
}

extern "C" void kernel_launch(void* const* d_in, const int* in_sizes, int n_in,
                              void* d_out, int out_size, void* d_ws, size_t ws_size,
                              hipStream_t stream) {
    const float* x     = (const float*)d_in[0];
    const float* cond  = (const float*)d_in[1];
    const float* state = (const float*)d_in[2];
    const float* a_rg  = (const float*)d_in[3];
    const float* a_r1  = (const float*)d_in[4];
    const float* a_c1  = (const float*)d_in[5];
    const float* a_c2  = (const float*)d_in[6];
    const float* c_w   = (const float*)d_in[7];
    const float* c_b   = (const float*)d_in[8];
    float* out = (float*)d_out;

    const int B = in_sizes[1];          // cond is [B,1]
    float* cf_ws = (float*)d_ws;        // B*5 floats

    preamp_coef_kernel<<<dim3((B + 255) / 256), dim3(256), 0, stream>>>(
        cond, a_rg, a_r1, a_c1, a_c2, c_w, c_b, cf_ws, B);
    preamp_fft_kernel<<<dim3((B + 1) / 2), dim3(512), 0, stream>>>(
        x, state, cf_ws, out, B);
}